// Round 1
// baseline (1351.590 us; speedup 1.0000x reference)
//
#include <hip/hip_runtime.h>
#include <hip/hip_bf16.h>

#define NB 8
#define NS 2048
#define ND 1024
#define NC 4096
#define NM (NB*NS)   // 16384 rows of scores/A

typedef __attribute__((ext_vector_type(8))) short bf16x8;
typedef __attribute__((ext_vector_type(4))) float floatx4;

__device__ __forceinline__ unsigned short f2bf(float f) {
  unsigned int u = __builtin_bit_cast(unsigned int, f);
  u += 0x7fffu + ((u >> 16) & 1u);           // round-to-nearest-even
  return (unsigned short)(u >> 16);
}
__device__ __forceinline__ float bf2f(unsigned short h) {
  unsigned int u = ((unsigned int)h) << 16;
  return __builtin_bit_cast(float, u);
}

// ---------------------------------------------------------------------------
// GEMM1: scores[m,n] = sum_k x[m,k] * L[n,k]   (m=B*S=16384, n=C=4096, k=D=1024)
// 3-term bf16 split (hi*hi + lo*hi + hi*lo) for ~fp32 logit accuracy.
// 128x128 tile, BK=32, 4 waves (2x2), each wave 64x64 via 4x4 x 16x16x32 MFMA.
// LDS rows padded to 40 shorts (80 B): b128 fragment reads conflict-free.
// ---------------------------------------------------------------------------
__global__ __launch_bounds__(256, 2)
void gemm1_scores(const float* __restrict__ x, const float* __restrict__ L,
                  float* __restrict__ sc) {
  __shared__ unsigned short sAh[128*40];
  __shared__ unsigned short sAl[128*40];
  __shared__ unsigned short sBh[128*40];
  __shared__ unsigned short sBl[128*40];
  const int tid = threadIdx.x;
  const int m0 = blockIdx.y << 7;
  const int n0 = blockIdx.x << 7;
  const int w  = tid >> 6;
  const int l  = tid & 63;
  const int wm = (w >> 1) << 6;   // 0 / 64
  const int wn = (w & 1) << 6;
  const int lrow = l & 15;
  const int quad = l >> 4;

  floatx4 acc[4][4] = {};

  const int srow = tid >> 3;         // 0..31
  const int scol = (tid & 7) << 2;   // 0,4,..,28

  const float* xa = x + (size_t)(m0 + srow) * ND + scol;
  const float* lb = L + (size_t)(n0 + srow) * ND + scol;

  for (int k0 = 0; k0 < ND; k0 += 32) {
    float4 av[4], bv[4];
    #pragma unroll
    for (int p = 0; p < 4; ++p) {
      av[p] = *(const float4*)(xa + (size_t)(p*32) * ND + k0);
      bv[p] = *(const float4*)(lb + (size_t)(p*32) * ND + k0);
    }
    __syncthreads();
    #pragma unroll
    for (int p = 0; p < 4; ++p) {
      const int r = srow + p*32;
      ushort4 h, lo;
      h.x = f2bf(av[p].x); lo.x = f2bf(av[p].x - bf2f(h.x));
      h.y = f2bf(av[p].y); lo.y = f2bf(av[p].y - bf2f(h.y));
      h.z = f2bf(av[p].z); lo.z = f2bf(av[p].z - bf2f(h.z));
      h.w = f2bf(av[p].w); lo.w = f2bf(av[p].w - bf2f(h.w));
      *(ushort4*)&sAh[r*40 + scol] = h;
      *(ushort4*)&sAl[r*40 + scol] = lo;
      h.x = f2bf(bv[p].x); lo.x = f2bf(bv[p].x - bf2f(h.x));
      h.y = f2bf(bv[p].y); lo.y = f2bf(bv[p].y - bf2f(h.y));
      h.z = f2bf(bv[p].z); lo.z = f2bf(bv[p].z - bf2f(h.z));
      h.w = f2bf(bv[p].w); lo.w = f2bf(bv[p].w - bf2f(h.w));
      *(ushort4*)&sBh[r*40 + scol] = h;
      *(ushort4*)&sBl[r*40 + scol] = lo;
    }
    __syncthreads();
    bf16x8 ah[4], bh[4], t[4];
    #pragma unroll
    for (int i = 0; i < 4; ++i) ah[i] = *(const bf16x8*)&sAh[(wm + i*16 + lrow)*40 + quad*8];
    #pragma unroll
    for (int j = 0; j < 4; ++j) bh[j] = *(const bf16x8*)&sBh[(wn + j*16 + lrow)*40 + quad*8];
    #pragma unroll
    for (int i = 0; i < 4; ++i)
      #pragma unroll
      for (int j = 0; j < 4; ++j)
        acc[i][j] = __builtin_amdgcn_mfma_f32_16x16x32_bf16(ah[i], bh[j], acc[i][j], 0, 0, 0);
    #pragma unroll
    for (int i = 0; i < 4; ++i) t[i] = *(const bf16x8*)&sAl[(wm + i*16 + lrow)*40 + quad*8];
    #pragma unroll
    for (int i = 0; i < 4; ++i)
      #pragma unroll
      for (int j = 0; j < 4; ++j)
        acc[i][j] = __builtin_amdgcn_mfma_f32_16x16x32_bf16(t[i], bh[j], acc[i][j], 0, 0, 0);
    #pragma unroll
    for (int j = 0; j < 4; ++j) t[j] = *(const bf16x8*)&sBl[(wn + j*16 + lrow)*40 + quad*8];
    #pragma unroll
    for (int i = 0; i < 4; ++i)
      #pragma unroll
      for (int j = 0; j < 4; ++j)
        acc[i][j] = __builtin_amdgcn_mfma_f32_16x16x32_bf16(ah[i], t[j], acc[i][j], 0, 0, 0);
  }

  // C/D layout: col = lane&15, row = quad*4 + reg
  float* op = sc + (size_t)(m0 + wm + quad*4) * NC + (n0 + wn + lrow);
  #pragma unroll
  for (int i = 0; i < 4; ++i)
    #pragma unroll
    for (int r = 0; r < 4; ++r)
      #pragma unroll
      for (int j = 0; j < 4; ++j)
        op[(size_t)(i*16 + r) * NC + j*16] = acc[i][j][r];
}

// ---------------------------------------------------------------------------
// Softmax over last dim (4096) of A, in place. One block per row.
// ---------------------------------------------------------------------------
__global__ __launch_bounds__(256)
void softmax_rows(float* __restrict__ A) {
  float* row = A + (size_t)blockIdx.x * NC;
  const int tid = threadIdx.x;
  float4 v[4];
  float mx = -3.0e38f;
  #pragma unroll
  for (int i = 0; i < 4; ++i) {
    v[i] = *(const float4*)(row + (tid << 2) + (i << 10));
    mx = fmaxf(mx, fmaxf(fmaxf(v[i].x, v[i].y), fmaxf(v[i].z, v[i].w)));
  }
  #pragma unroll
  for (int off = 32; off > 0; off >>= 1) mx = fmaxf(mx, __shfl_xor(mx, off));
  __shared__ float red[4];
  if ((tid & 63) == 0) red[tid >> 6] = mx;
  __syncthreads();
  mx = fmaxf(fmaxf(red[0], red[1]), fmaxf(red[2], red[3]));
  float s = 0.f;
  #pragma unroll
  for (int i = 0; i < 4; ++i) {
    v[i].x = __expf(v[i].x - mx); v[i].y = __expf(v[i].y - mx);
    v[i].z = __expf(v[i].z - mx); v[i].w = __expf(v[i].w - mx);
    s += (v[i].x + v[i].y) + (v[i].z + v[i].w);
  }
  #pragma unroll
  for (int off = 32; off > 0; off >>= 1) s += __shfl_xor(s, off);
  __syncthreads();
  if ((tid & 63) == 0) red[tid >> 6] = s;
  __syncthreads();
  s = (red[0] + red[1]) + (red[2] + red[3]);
  const float inv = 1.0f / s;
  #pragma unroll
  for (int i = 0; i < 4; ++i) {
    v[i].x *= inv; v[i].y *= inv; v[i].z *= inv; v[i].w *= inv;
    *(float4*)(row + (tid << 2) + (i << 10)) = v[i];
  }
}

// ---------------------------------------------------------------------------
// GEMM2 (per batch): O[c,d] = sum_s A[s,c] * x[s,d]   (c=4096, d=1024, s=2048)
// Both operands are k(=s)-major in memory -> transpose during staging.
// Lane map spair=t&15, c4=(t>>4)*4 makes packed-b32 LDS writes 2-way (free).
// ---------------------------------------------------------------------------
__global__ __launch_bounds__(256, 2)
void gemm2_out(const float* __restrict__ A, const float* __restrict__ x,
               float* __restrict__ out) {
  __shared__ unsigned short sA[128*40];
  __shared__ unsigned short sX[128*40];
  const int tid = threadIdx.x;
  const float* Ab = A + (size_t)blockIdx.z * NS * NC;
  const float* xb = x + (size_t)blockIdx.z * NS * ND;
  float* ob = out + (size_t)blockIdx.z * NC * ND;
  const int m0 = blockIdx.y << 7;  // c
  const int n0 = blockIdx.x << 7;  // d
  const int w  = tid >> 6;
  const int l  = tid & 63;
  const int wm = (w >> 1) << 6;
  const int wn = (w & 1) << 6;
  const int lrow = l & 15;
  const int quad = l >> 4;

  floatx4 acc[4][4] = {};

  const int sp0 = tid & 15;    // s-pair index (s = 2*sp0, 2*sp0+1)
  const int cg0 = tid >> 4;    // 0..15, pass 1 adds 16 -> c-granule

  for (int k0 = 0; k0 < NS; k0 += 32) {
    float4 a[2][2], xv[2][2];
    const int s = k0 + sp0*2;
    #pragma unroll
    for (int p = 0; p < 2; ++p) {
      const int c4 = (cg0 + p*16) << 2;
      a[p][0]  = *(const float4*)(Ab + (size_t)s     * NC + m0 + c4);
      a[p][1]  = *(const float4*)(Ab + (size_t)(s+1) * NC + m0 + c4);
      xv[p][0] = *(const float4*)(xb + (size_t)s     * ND + n0 + c4);
      xv[p][1] = *(const float4*)(xb + (size_t)(s+1) * ND + n0 + c4);
    }
    __syncthreads();
    #pragma unroll
    for (int p = 0; p < 2; ++p) {
      const int c4 = (cg0 + p*16) << 2;
      const float* fa0 = (const float*)&a[p][0];
      const float* fa1 = (const float*)&a[p][1];
      const float* fx0 = (const float*)&xv[p][0];
      const float* fx1 = (const float*)&xv[p][1];
      #pragma unroll
      for (int i = 0; i < 4; ++i) {
        const unsigned int pa = (unsigned int)f2bf(fa0[i]) | ((unsigned int)f2bf(fa1[i]) << 16);
        const unsigned int px = (unsigned int)f2bf(fx0[i]) | ((unsigned int)f2bf(fx1[i]) << 16);
        *(unsigned int*)&sA[(c4 + i)*40 + sp0*2] = pa;
        *(unsigned int*)&sX[(c4 + i)*40 + sp0*2] = px;
      }
    }
    __syncthreads();
    bf16x8 af[4], bg[4];
    #pragma unroll
    for (int i = 0; i < 4; ++i) af[i] = *(const bf16x8*)&sA[(wm + i*16 + lrow)*40 + quad*8];
    #pragma unroll
    for (int j = 0; j < 4; ++j) bg[j] = *(const bf16x8*)&sX[(wn + j*16 + lrow)*40 + quad*8];
    #pragma unroll
    for (int i = 0; i < 4; ++i)
      #pragma unroll
      for (int j = 0; j < 4; ++j)
        acc[i][j] = __builtin_amdgcn_mfma_f32_16x16x32_bf16(af[i], bg[j], acc[i][j], 0, 0, 0);
  }

  float* op = ob + (size_t)(m0 + wm + quad*4) * ND + (n0 + wn + lrow);
  #pragma unroll
  for (int i = 0; i < 4; ++i)
    #pragma unroll
    for (int r = 0; r < 4; ++r)
      #pragma unroll
      for (int j = 0; j < 4; ++j)
        op[(size_t)(i*16 + r) * ND + j*16] = acc[i][j][r];
}

extern "C" void kernel_launch(void* const* d_in, const int* in_sizes, int n_in,
                              void* d_out, int out_size, void* d_ws, size_t ws_size,
                              hipStream_t stream) {
  const float* x = (const float*)d_in[0];        // [B,S,D]
  const float* L = (const float*)d_in[1];        // [C,D]
  float* out = (float*)d_out;                    // [B,C,D] then A [B,S,C]
  float* A   = out + (size_t)NB * NC * ND;

  gemm1_scores<<<dim3(NC/128, NM/128), 256, 0, stream>>>(x, L, A);
  softmax_rows<<<dim3(NM), 256, 0, stream>>>(A);
  gemm2_out<<<dim3(ND/128, NC/128, NB), 256, 0, stream>>>(A, x, out);
}

// Round 2
// 1165.552 us; speedup vs baseline: 1.1596x; 1.1596x over previous
//
#include <hip/hip_runtime.h>
#include <hip/hip_bf16.h>

#define NB 8
#define NS 2048
#define ND 1024
#define NC 4096
#define NM (NB*NS)   // 16384 rows of scores/A

typedef __attribute__((ext_vector_type(8))) short bf16x8;
typedef __attribute__((ext_vector_type(4))) float floatx4;
typedef unsigned short ushort_t;

__device__ __forceinline__ unsigned short f2bf(float f) {
  unsigned int u = __builtin_bit_cast(unsigned int, f);
  u += 0x7fffu + ((u >> 16) & 1u);           // round-to-nearest-even
  return (unsigned short)(u >> 16);
}
__device__ __forceinline__ float bf2f(unsigned short h) {
  unsigned int u = ((unsigned int)h) << 16;
  return __builtin_bit_cast(float, u);
}

// async global->LDS, 16 B per lane. LDS dest = wave-uniform base + lane*16.
__device__ __forceinline__ void load_lds16(const void* g, void* s) {
  __builtin_amdgcn_global_load_lds(
      (const __attribute__((address_space(1))) char*)g,
      (__attribute__((address_space(3))) char*)s, 16, 0, 0);
}

// ===========================================================================
// v2 path (uses d_ws; requires ~252 MB)
// ===========================================================================

// L [C,D] fp32 -> L_hi, L_lo bf16 (elementwise)
__global__ __launch_bounds__(256)
void prep_L(const float* __restrict__ L, ushort_t* __restrict__ Lh,
            ushort_t* __restrict__ Ll) {
  const size_t i = ((size_t)blockIdx.x * 256 + threadIdx.x) * 4;
  float4 v = *(const float4*)(L + i);
  ushort4 h, lo;
  h.x = f2bf(v.x); lo.x = f2bf(v.x - bf2f(h.x));
  h.y = f2bf(v.y); lo.y = f2bf(v.y - bf2f(h.y));
  h.z = f2bf(v.z); lo.z = f2bf(v.z - bf2f(h.z));
  h.w = f2bf(v.w); lo.w = f2bf(v.w - bf2f(h.w));
  *(ushort4*)(Lh + i) = h;
  *(ushort4*)(Ll + i) = lo;
}

// x [B,S,D] fp32 -> x_hi,x_lo bf16 [B,S,D] and x_T bf16 [B,D,S]
// block: 32 s-rows x 256 d-cols. sp=t&15 (s-pair), cg=t>>4.
__global__ __launch_bounds__(256)
void prep_x(const float* __restrict__ x, ushort_t* __restrict__ xh,
            ushort_t* __restrict__ xl, ushort_t* __restrict__ xT) {
  __shared__ unsigned int tile[256 * 17];  // [d_rel][s-pair], pitch 17 dwords
  const int b = blockIdx.z;
  const int s0 = blockIdx.y << 5;
  const int d0 = blockIdx.x << 8;
  const int tid = threadIdx.x;
  const int sp = tid & 15, cg = tid >> 4;
  const int r0 = 2 * sp, r1 = r0 + 1;
  const float* xb = x + (size_t)b * NS * ND;
  ushort_t* xhb = xh + (size_t)b * NS * ND;
  ushort_t* xlb = xl + (size_t)b * NS * ND;
  #pragma unroll
  for (int i = 0; i < 4; ++i) {
    const int crel = cg * 4 + i * 64;
    const int col = d0 + crel;
    float4 v0 = *(const float4*)(xb + (size_t)(s0 + r0) * ND + col);
    float4 v1 = *(const float4*)(xb + (size_t)(s0 + r1) * ND + col);
    ushort4 h0, l0, h1, l1;
    h0.x = f2bf(v0.x); l0.x = f2bf(v0.x - bf2f(h0.x));
    h0.y = f2bf(v0.y); l0.y = f2bf(v0.y - bf2f(h0.y));
    h0.z = f2bf(v0.z); l0.z = f2bf(v0.z - bf2f(h0.z));
    h0.w = f2bf(v0.w); l0.w = f2bf(v0.w - bf2f(h0.w));
    h1.x = f2bf(v1.x); l1.x = f2bf(v1.x - bf2f(h1.x));
    h1.y = f2bf(v1.y); l1.y = f2bf(v1.y - bf2f(h1.y));
    h1.z = f2bf(v1.z); l1.z = f2bf(v1.z - bf2f(h1.z));
    h1.w = f2bf(v1.w); l1.w = f2bf(v1.w - bf2f(h1.w));
    *(ushort4*)(xhb + (size_t)(s0 + r0) * ND + col) = h0;
    *(ushort4*)(xlb + (size_t)(s0 + r0) * ND + col) = l0;
    *(ushort4*)(xhb + (size_t)(s0 + r1) * ND + col) = h1;
    *(ushort4*)(xlb + (size_t)(s0 + r1) * ND + col) = l1;
    tile[(crel + 0) * 17 + sp] = (unsigned)h0.x | ((unsigned)h1.x << 16);
    tile[(crel + 1) * 17 + sp] = (unsigned)h0.y | ((unsigned)h1.y << 16);
    tile[(crel + 2) * 17 + sp] = (unsigned)h0.z | ((unsigned)h1.z << 16);
    tile[(crel + 3) * 17 + sp] = (unsigned)h0.w | ((unsigned)h1.w << 16);
  }
  __syncthreads();
  unsigned tmp[16];
  #pragma unroll
  for (int k = 0; k < 16; ++k) tmp[k] = tile[tid * 17 + k];
  ushort_t* dst = xT + ((size_t)b * ND + d0 + tid) * NS + s0;
  #pragma unroll
  for (int k = 0; k < 4; ++k) *(uint4*)(dst + k * 8) = *(uint4*)&tmp[k * 4];
}

// GEMM1: scores = x . L^T via 3-term bf16 split; pure global_load_lds staging.
__global__ __launch_bounds__(256, 2)
void gemm1_v2(const ushort_t* __restrict__ xh, const ushort_t* __restrict__ xl,
              const ushort_t* __restrict__ Lh, const ushort_t* __restrict__ Ll,
              float* __restrict__ sc) {
  __shared__ ushort_t sAh[128 * 32];
  __shared__ ushort_t sAl[128 * 32];
  __shared__ ushort_t sBh[128 * 32];
  __shared__ ushort_t sBl[128 * 32];
  const int tid = threadIdx.x;
  const int m0 = blockIdx.y << 7;
  const int n0 = blockIdx.x << 7;
  const int w = tid >> 6, l = tid & 63;
  const int wm = (w >> 1) << 6;
  const int wn = (w & 1) << 6;
  const int lrow = l & 15, quad = l >> 4;
  const int srow = l >> 2;          // 0..15
  const int skol = (l & 3) << 3;    // 0,8,16,24

  floatx4 acc[4][4] = {};

  for (int k0 = 0; k0 < ND; k0 += 32) {
    __syncthreads();
    #pragma unroll
    for (int q = 0; q < 2; ++q) {
      const int row = w * 32 + q * 16 + srow;
      const size_t ga = (size_t)(m0 + row) * ND + k0 + skol;
      const size_t gb = (size_t)(n0 + row) * ND + k0 + skol;
      const int lo = w * 1024 + q * 512;   // element offset (shorts)
      load_lds16(xh + ga, &sAh[lo]);
      load_lds16(xl + ga, &sAl[lo]);
      load_lds16(Lh + gb, &sBh[lo]);
      load_lds16(Ll + gb, &sBl[lo]);
    }
    __syncthreads();
    bf16x8 ah[4], bh[4], t[4];
    #pragma unroll
    for (int i = 0; i < 4; ++i) ah[i] = *(const bf16x8*)&sAh[(wm + i*16 + lrow)*32 + quad*8];
    #pragma unroll
    for (int j = 0; j < 4; ++j) bh[j] = *(const bf16x8*)&sBh[(wn + j*16 + lrow)*32 + quad*8];
    #pragma unroll
    for (int i = 0; i < 4; ++i)
      #pragma unroll
      for (int j = 0; j < 4; ++j)
        acc[i][j] = __builtin_amdgcn_mfma_f32_16x16x32_bf16(ah[i], bh[j], acc[i][j], 0, 0, 0);
    #pragma unroll
    for (int i = 0; i < 4; ++i) t[i] = *(const bf16x8*)&sAl[(wm + i*16 + lrow)*32 + quad*8];
    #pragma unroll
    for (int i = 0; i < 4; ++i)
      #pragma unroll
      for (int j = 0; j < 4; ++j)
        acc[i][j] = __builtin_amdgcn_mfma_f32_16x16x32_bf16(t[i], bh[j], acc[i][j], 0, 0, 0);
    #pragma unroll
    for (int j = 0; j < 4; ++j) t[j] = *(const bf16x8*)&sBl[(wn + j*16 + lrow)*32 + quad*8];
    #pragma unroll
    for (int i = 0; i < 4; ++i)
      #pragma unroll
      for (int j = 0; j < 4; ++j)
        acc[i][j] = __builtin_amdgcn_mfma_f32_16x16x32_bf16(ah[i], t[j], acc[i][j], 0, 0, 0);
  }

  float* op = sc + (size_t)(m0 + wm + quad * 4) * NC + (n0 + wn + lrow);
  #pragma unroll
  for (int i = 0; i < 4; ++i)
    #pragma unroll
    for (int r = 0; r < 4; ++r)
      #pragma unroll
      for (int j = 0; j < 4; ++j)
        op[(size_t)(i * 16 + r) * NC + j * 16] = acc[i][j][r];
}

// Fused softmax + bf16 transpose. Block = 32 rows (one batch) x full C.
// Writes A fp32 in place and A_T[b,c,s] bf16 to ws.
__global__ __launch_bounds__(256)
void softmax_T(float* __restrict__ A, ushort_t* __restrict__ AT) {
  __shared__ float sm[32], sli[32];
  __shared__ unsigned int tile[256 * 17];  // [c_rel][s-pair]
  const int s0 = blockIdx.x << 5;
  const int b = s0 >> 11;
  const int sl0 = s0 & (NS - 1);
  const int tid = threadIdx.x;
  const int w = tid >> 6, l = tid & 63;

  // phase 1: online (max,sum) per row; wave w handles rows w*8..w*8+8
  float m[8], su[8];
  #pragma unroll
  for (int r = 0; r < 8; ++r) { m[r] = -3.0e38f; su[r] = 0.f; }
  for (int ch = 0; ch < 16; ++ch) {
    #pragma unroll
    for (int r = 0; r < 8; ++r) {
      float4 v = *(const float4*)(A + (size_t)(s0 + w * 8 + r) * NC + ch * 256 + (l << 2));
      float mx = fmaxf(fmaxf(v.x, v.y), fmaxf(v.z, v.w));
      float nm = fmaxf(m[r], mx);
      su[r] = su[r] * __expf(m[r] - nm) +
              __expf(v.x - nm) + __expf(v.y - nm) + __expf(v.z - nm) + __expf(v.w - nm);
      m[r] = nm;
    }
  }
  #pragma unroll
  for (int r = 0; r < 8; ++r) {
    #pragma unroll
    for (int off = 32; off; off >>= 1) {
      float om = __shfl_xor(m[r], off);
      float os = __shfl_xor(su[r], off);
      float nm = fmaxf(m[r], om);
      su[r] = su[r] * __expf(m[r] - nm) + os * __expf(om - nm);
      m[r] = nm;
    }
    if (l == 0) { sm[w * 8 + r] = m[r]; sli[w * 8 + r] = 1.0f / su[r]; }
  }
  __syncthreads();

  // phase 2: normalize + write fp32 + transpose bf16
  const int sp = tid & 15, cg = tid >> 4;
  const int r0 = 2 * sp, r1 = r0 + 1;
  const float M0 = sm[r0], I0 = sli[r0];
  const float M1 = sm[r1], I1 = sli[r1];
  float* A0 = A + (size_t)(s0 + r0) * NC;
  float* A1 = A + (size_t)(s0 + r1) * NC;
  for (int ch = 0; ch < 16; ++ch) {
    const int cb = ch << 8;
    #pragma unroll
    for (int i = 0; i < 4; ++i) {
      const int crel = cg * 4 + i * 64;
      float4 v0 = *(const float4*)(A0 + cb + crel);
      float4 v1 = *(const float4*)(A1 + cb + crel);
      float4 p0, p1;
      p0.x = __expf(v0.x - M0) * I0; p0.y = __expf(v0.y - M0) * I0;
      p0.z = __expf(v0.z - M0) * I0; p0.w = __expf(v0.w - M0) * I0;
      p1.x = __expf(v1.x - M1) * I1; p1.y = __expf(v1.y - M1) * I1;
      p1.z = __expf(v1.z - M1) * I1; p1.w = __expf(v1.w - M1) * I1;
      *(float4*)(A0 + cb + crel) = p0;
      *(float4*)(A1 + cb + crel) = p1;
      tile[(crel + 0) * 17 + sp] = (unsigned)f2bf(p0.x) | ((unsigned)f2bf(p1.x) << 16);
      tile[(crel + 1) * 17 + sp] = (unsigned)f2bf(p0.y) | ((unsigned)f2bf(p1.y) << 16);
      tile[(crel + 2) * 17 + sp] = (unsigned)f2bf(p0.z) | ((unsigned)f2bf(p1.z) << 16);
      tile[(crel + 3) * 17 + sp] = (unsigned)f2bf(p0.w) | ((unsigned)f2bf(p1.w) << 16);
    }
    __syncthreads();
    unsigned tmp[16];
    #pragma unroll
    for (int k = 0; k < 16; ++k) tmp[k] = tile[tid * 17 + k];
    ushort_t* dst = AT + ((size_t)b * NC + cb + tid) * NS + sl0;
    #pragma unroll
    for (int k = 0; k < 4; ++k) *(uint4*)(dst + k * 8) = *(uint4*)&tmp[k * 4];
    __syncthreads();
  }
}

// GEMM2: O[c,d] = sum_s A_T[c,s] * x_T[d,s] — pure m97-shape bf16 GEMM.
__global__ __launch_bounds__(256, 2)
void gemm2_v2(const ushort_t* __restrict__ AT, const ushort_t* __restrict__ xT,
              float* __restrict__ out) {
  __shared__ ushort_t sA[128 * 32];
  __shared__ ushort_t sX[128 * 32];
  const int tid = threadIdx.x;
  const int b = blockIdx.z;
  const ushort_t* Ab = AT + (size_t)b * NC * NS;
  const ushort_t* xb = xT + (size_t)b * ND * NS;
  float* ob = out + (size_t)b * NC * ND;
  const int m0 = blockIdx.y << 7;  // c
  const int n0 = blockIdx.x << 7;  // d
  const int w = tid >> 6, l = tid & 63;
  const int wm = (w >> 1) << 6;
  const int wn = (w & 1) << 6;
  const int lrow = l & 15, quad = l >> 4;
  const int srow = l >> 2;
  const int skol = (l & 3) << 3;

  floatx4 acc[4][4] = {};

  for (int k0 = 0; k0 < NS; k0 += 32) {
    __syncthreads();
    #pragma unroll
    for (int q = 0; q < 2; ++q) {
      const int row = w * 32 + q * 16 + srow;
      const int lo = w * 1024 + q * 512;
      load_lds16(Ab + (size_t)(m0 + row) * NS + k0 + skol, &sA[lo]);
      load_lds16(xb + (size_t)(n0 + row) * NS + k0 + skol, &sX[lo]);
    }
    __syncthreads();
    bf16x8 af[4], bg[4];
    #pragma unroll
    for (int i = 0; i < 4; ++i) af[i] = *(const bf16x8*)&sA[(wm + i*16 + lrow)*32 + quad*8];
    #pragma unroll
    for (int j = 0; j < 4; ++j) bg[j] = *(const bf16x8*)&sX[(wn + j*16 + lrow)*32 + quad*8];
    #pragma unroll
    for (int i = 0; i < 4; ++i)
      #pragma unroll
      for (int j = 0; j < 4; ++j)
        acc[i][j] = __builtin_amdgcn_mfma_f32_16x16x32_bf16(af[i], bg[j], acc[i][j], 0, 0, 0);
  }

  float* op = ob + (size_t)(m0 + wm + quad * 4) * ND + (n0 + wn + lrow);
  #pragma unroll
  for (int i = 0; i < 4; ++i)
    #pragma unroll
    for (int r = 0; r < 4; ++r)
      #pragma unroll
      for (int j = 0; j < 4; ++j)
        op[(size_t)(i * 16 + r) * ND + j * 16] = acc[i][j][r];
}

// ===========================================================================
// v1 fallback path (no workspace) — proven round-1 kernels
// ===========================================================================

__global__ __launch_bounds__(256, 2)
void gemm1_scores(const float* __restrict__ x, const float* __restrict__ L,
                  float* __restrict__ sc) {
  __shared__ unsigned short sAh[128*40];
  __shared__ unsigned short sAl[128*40];
  __shared__ unsigned short sBh[128*40];
  __shared__ unsigned short sBl[128*40];
  const int tid = threadIdx.x;
  const int m0 = blockIdx.y << 7;
  const int n0 = blockIdx.x << 7;
  const int w  = tid >> 6;
  const int l  = tid & 63;
  const int wm = (w >> 1) << 6;
  const int wn = (w & 1) << 6;
  const int lrow = l & 15;
  const int quad = l >> 4;
  floatx4 acc[4][4] = {};
  const int srow = tid >> 3;
  const int scol = (tid & 7) << 2;
  const float* xa = x + (size_t)(m0 + srow) * ND + scol;
  const float* lb = L + (size_t)(n0 + srow) * ND + scol;
  for (int k0 = 0; k0 < ND; k0 += 32) {
    float4 av[4], bv[4];
    #pragma unroll
    for (int p = 0; p < 4; ++p) {
      av[p] = *(const float4*)(xa + (size_t)(p*32) * ND + k0);
      bv[p] = *(const float4*)(lb + (size_t)(p*32) * ND + k0);
    }
    __syncthreads();
    #pragma unroll
    for (int p = 0; p < 4; ++p) {
      const int r = srow + p*32;
      ushort4 h, lo;
      h.x = f2bf(av[p].x); lo.x = f2bf(av[p].x - bf2f(h.x));
      h.y = f2bf(av[p].y); lo.y = f2bf(av[p].y - bf2f(h.y));
      h.z = f2bf(av[p].z); lo.z = f2bf(av[p].z - bf2f(h.z));
      h.w = f2bf(av[p].w); lo.w = f2bf(av[p].w - bf2f(h.w));
      *(ushort4*)&sAh[r*40 + scol] = h;
      *(ushort4*)&sAl[r*40 + scol] = lo;
      h.x = f2bf(bv[p].x); lo.x = f2bf(bv[p].x - bf2f(h.x));
      h.y = f2bf(bv[p].y); lo.y = f2bf(bv[p].y - bf2f(h.y));
      h.z = f2bf(bv[p].z); lo.z = f2bf(bv[p].z - bf2f(h.z));
      h.w = f2bf(bv[p].w); lo.w = f2bf(bv[p].w - bf2f(h.w));
      *(ushort4*)&sBh[r*40 + scol] = h;
      *(ushort4*)&sBl[r*40 + scol] = lo;
    }
    __syncthreads();
    bf16x8 ah[4], bh[4], t[4];
    #pragma unroll
    for (int i = 0; i < 4; ++i) ah[i] = *(const bf16x8*)&sAh[(wm + i*16 + lrow)*40 + quad*8];
    #pragma unroll
    for (int j = 0; j < 4; ++j) bh[j] = *(const bf16x8*)&sBh[(wn + j*16 + lrow)*40 + quad*8];
    #pragma unroll
    for (int i = 0; i < 4; ++i)
      #pragma unroll
      for (int j = 0; j < 4; ++j)
        acc[i][j] = __builtin_amdgcn_mfma_f32_16x16x32_bf16(ah[i], bh[j], acc[i][j], 0, 0, 0);
    #pragma unroll
    for (int i = 0; i < 4; ++i) t[i] = *(const bf16x8*)&sAl[(wm + i*16 + lrow)*40 + quad*8];
    #pragma unroll
    for (int i = 0; i < 4; ++i)
      #pragma unroll
      for (int j = 0; j < 4; ++j)
        acc[i][j] = __builtin_amdgcn_mfma_f32_16x16x32_bf16(t[i], bh[j], acc[i][j], 0, 0, 0);
    #pragma unroll
    for (int j = 0; j < 4; ++j) t[j] = *(const bf16x8*)&sBl[(wn + j*16 + lrow)*40 + quad*8];
    #pragma unroll
    for (int i = 0; i < 4; ++i)
      #pragma unroll
      for (int j = 0; j < 4; ++j)
        acc[i][j] = __builtin_amdgcn_mfma_f32_16x16x32_bf16(ah[i], t[j], acc[i][j], 0, 0, 0);
  }
  float* op = sc + (size_t)(m0 + wm + quad*4) * NC + (n0 + wn + lrow);
  #pragma unroll
  for (int i = 0; i < 4; ++i)
    #pragma unroll
    for (int r = 0; r < 4; ++r)
      #pragma unroll
      for (int j = 0; j < 4; ++j)
        op[(size_t)(i*16 + r) * NC + j*16] = acc[i][j][r];
}

__global__ __launch_bounds__(256)
void softmax_rows(float* __restrict__ A) {
  float* row = A + (size_t)blockIdx.x * NC;
  const int tid = threadIdx.x;
  float4 v[4];
  float mx = -3.0e38f;
  #pragma unroll
  for (int i = 0; i < 4; ++i) {
    v[i] = *(const float4*)(row + (tid << 2) + (i << 10));
    mx = fmaxf(mx, fmaxf(fmaxf(v[i].x, v[i].y), fmaxf(v[i].z, v[i].w)));
  }
  #pragma unroll
  for (int off = 32; off > 0; off >>= 1) mx = fmaxf(mx, __shfl_xor(mx, off));
  __shared__ float red[4];
  if ((tid & 63) == 0) red[tid >> 6] = mx;
  __syncthreads();
  mx = fmaxf(fmaxf(red[0], red[1]), fmaxf(red[2], red[3]));
  float s = 0.f;
  #pragma unroll
  for (int i = 0; i < 4; ++i) {
    v[i].x = __expf(v[i].x - mx); v[i].y = __expf(v[i].y - mx);
    v[i].z = __expf(v[i].z - mx); v[i].w = __expf(v[i].w - mx);
    s += (v[i].x + v[i].y) + (v[i].z + v[i].w);
  }
  #pragma unroll
  for (int off = 32; off > 0; off >>= 1) s += __shfl_xor(s, off);
  __syncthreads();
  if ((tid & 63) == 0) red[tid >> 6] = s;
  __syncthreads();
  s = (red[0] + red[1]) + (red[2] + red[3]);
  const float inv = 1.0f / s;
  #pragma unroll
  for (int i = 0; i < 4; ++i) {
    v[i].x *= inv; v[i].y *= inv; v[i].z *= inv; v[i].w *= inv;
    *(float4*)(row + (tid << 2) + (i << 10)) = v[i];
  }
}

__global__ __launch_bounds__(256, 2)
void gemm2_out(const float* __restrict__ A, const float* __restrict__ x,
               float* __restrict__ out) {
  __shared__ unsigned short sA[128*40];
  __shared__ unsigned short sX[128*40];
  const int tid = threadIdx.x;
  const float* Ab = A + (size_t)blockIdx.z * NS * NC;
  const float* xb = x + (size_t)blockIdx.z * NS * ND;
  float* ob = out + (size_t)blockIdx.z * NC * ND;
  const int m0 = blockIdx.y << 7;
  const int n0 = blockIdx.x << 7;
  const int w  = tid >> 6;
  const int l  = tid & 63;
  const int wm = (w >> 1) << 6;
  const int wn = (w & 1) << 6;
  const int lrow = l & 15;
  const int quad = l >> 4;
  floatx4 acc[4][4] = {};
  const int sp0 = tid & 15;
  const int cg0 = tid >> 4;
  for (int k0 = 0; k0 < NS; k0 += 32) {
    float4 a[2][2], xv[2][2];
    const int s = k0 + sp0*2;
    #pragma unroll
    for (int p = 0; p < 2; ++p) {
      const int c4 = (cg0 + p*16) << 2;
      a[p][0]  = *(const float4*)(Ab + (size_t)s     * NC + m0 + c4);
      a[p][1]  = *(const float4*)(Ab + (size_t)(s+1) * NC + m0 + c4);
      xv[p][0] = *(const float4*)(xb + (size_t)s     * ND + n0 + c4);
      xv[p][1] = *(const float4*)(xb + (size_t)(s+1) * ND + n0 + c4);
    }
    __syncthreads();
    #pragma unroll
    for (int p = 0; p < 2; ++p) {
      const int c4 = (cg0 + p*16) << 2;
      const float* fa0 = (const float*)&a[p][0];
      const float* fa1 = (const float*)&a[p][1];
      const float* fx0 = (const float*)&xv[p][0];
      const float* fx1 = (const float*)&xv[p][1];
      #pragma unroll
      for (int i = 0; i < 4; ++i) {
        const unsigned int pa = (unsigned int)f2bf(fa0[i]) | ((unsigned int)f2bf(fa1[i]) << 16);
        const unsigned int px = (unsigned int)f2bf(fx0[i]) | ((unsigned int)f2bf(fx1[i]) << 16);
        *(unsigned int*)&sA[(c4 + i)*40 + sp0*2] = pa;
        *(unsigned int*)&sX[(c4 + i)*40 + sp0*2] = px;
      }
    }
    __syncthreads();
    bf16x8 af[4], bg[4];
    #pragma unroll
    for (int i = 0; i < 4; ++i) af[i] = *(const bf16x8*)&sA[(wm + i*16 + lrow)*40 + quad*8];
    #pragma unroll
    for (int j = 0; j < 4; ++j) bg[j] = *(const bf16x8*)&sX[(wn + j*16 + lrow)*40 + quad*8];
    #pragma unroll
    for (int i = 0; i < 4; ++i)
      #pragma unroll
      for (int j = 0; j < 4; ++j)
        acc[i][j] = __builtin_amdgcn_mfma_f32_16x16x32_bf16(af[i], bg[j], acc[i][j], 0, 0, 0);
  }
  float* op = ob + (size_t)(m0 + wm + quad*4) * ND + (n0 + wn + lrow);
  #pragma unroll
  for (int i = 0; i < 4; ++i)
    #pragma unroll
    for (int r = 0; r < 4; ++r)
      #pragma unroll
      for (int j = 0; j < 4; ++j)
        op[(size_t)(i*16 + r) * ND + j*16] = acc[i][j][r];
}

// ===========================================================================

extern "C" void kernel_launch(void* const* d_in, const int* in_sizes, int n_in,
                              void* d_out, int out_size, void* d_ws, size_t ws_size,
                              hipStream_t stream) {
  const float* x = (const float*)d_in[0];        // [B,S,D]
  const float* L = (const float*)d_in[1];        // [C,D]
  float* out = (float*)d_out;                    // [B,C,D] then A [B,S,C]
  float* A   = out + (size_t)NB * NC * ND;

  const size_t EL_X  = (size_t)NB * NS * ND;   // 16,777,216
  const size_t EL_L  = (size_t)NC * ND;        //  4,194,304
  const size_t EL_AT = (size_t)NB * NC * NS;   // 67,108,864
  const size_t need  = (3 * EL_X + 2 * EL_L + EL_AT) * sizeof(ushort_t);

  if (ws_size >= need) {
    ushort_t* xh = (ushort_t*)d_ws;
    ushort_t* xl = xh + EL_X;
    ushort_t* xT = xl + EL_X;
    ushort_t* Lh = xT + EL_X;
    ushort_t* Ll = Lh + EL_L;
    ushort_t* AT = Ll + EL_L;
    prep_L<<<dim3((NC * ND) / 1024), 256, 0, stream>>>(L, Lh, Ll);
    prep_x<<<dim3(ND / 256, NS / 32, NB), 256, 0, stream>>>(x, xh, xl, xT);
    gemm1_v2<<<dim3(NC / 128, NM / 128), 256, 0, stream>>>(xh, xl, Lh, Ll, A);
    softmax_T<<<dim3(NM / 32), 256, 0, stream>>>(A, AT);
    gemm2_v2<<<dim3(ND / 128, NC / 128, NB), 256, 0, stream>>>(AT, xT, out);
  } else {
    gemm1_scores<<<dim3(NC / 128, NM / 128), 256, 0, stream>>>(x, L, A);
    softmax_rows<<<dim3(NM), 256, 0, stream>>>(A);
    gemm2_out<<<dim3(ND / 128, NC / 128, NB), 256, 0, stream>>>(A, x, out);
  }
}

// Round 3
// 1124.539 us; speedup vs baseline: 1.2019x; 1.0365x over previous
//
#include <hip/hip_runtime.h>
#include <hip/hip_bf16.h>

#define NB 8
#define NS 2048
#define ND 1024
#define NC 4096
#define NM (NB*NS)   // 16384 rows of scores/A

typedef __attribute__((ext_vector_type(8))) short bf16x8;
typedef __attribute__((ext_vector_type(4))) float floatx4;
typedef unsigned short ushort_t;

__device__ __forceinline__ unsigned short f2bf(float f) {
  unsigned int u = __builtin_bit_cast(unsigned int, f);
  u += 0x7fffu + ((u >> 16) & 1u);           // round-to-nearest-even
  return (unsigned short)(u >> 16);
}
__device__ __forceinline__ float bf2f(unsigned short h) {
  unsigned int u = ((unsigned int)h) << 16;
  return __builtin_bit_cast(float, u);
}

// async global->LDS, 16 B per lane. LDS dest = wave-uniform base + lane*16.
__device__ __forceinline__ void load_lds16(const void* g, void* s) {
  __builtin_amdgcn_global_load_lds(
      (const __attribute__((address_space(1))) char*)g,
      (__attribute__((address_space(3))) char*)s, 16, 0, 0);
}

// ===========================================================================
// v3 path
// ===========================================================================

// L [C,D] fp32 -> L_hi, L_lo bf16 (elementwise)
__global__ __launch_bounds__(256)
void prep_L(const float* __restrict__ L, ushort_t* __restrict__ Lh,
            ushort_t* __restrict__ Ll) {
  const size_t i = ((size_t)blockIdx.x * 256 + threadIdx.x) * 4;
  float4 v = *(const float4*)(L + i);
  ushort4 h, lo;
  h.x = f2bf(v.x); lo.x = f2bf(v.x - bf2f(h.x));
  h.y = f2bf(v.y); lo.y = f2bf(v.y - bf2f(h.y));
  h.z = f2bf(v.z); lo.z = f2bf(v.z - bf2f(h.z));
  h.w = f2bf(v.w); lo.w = f2bf(v.w - bf2f(h.w));
  *(ushort4*)(Lh + i) = h;
  *(ushort4*)(Ll + i) = lo;
}

// x [B,S,D] fp32 -> x_hi,x_lo bf16 [B,S,D] and x_T bf16 [B,D,S]
__global__ __launch_bounds__(256)
void prep_x(const float* __restrict__ x, ushort_t* __restrict__ xh,
            ushort_t* __restrict__ xl, ushort_t* __restrict__ xT) {
  __shared__ unsigned int tile[256 * 17];  // [d_rel][s-pair], pitch 17 dwords
  const int b = blockIdx.z;
  const int s0 = blockIdx.y << 5;
  const int d0 = blockIdx.x << 8;
  const int tid = threadIdx.x;
  const int sp = tid & 15, cg = tid >> 4;
  const int r0 = 2 * sp, r1 = r0 + 1;
  const float* xb = x + (size_t)b * NS * ND;
  ushort_t* xhb = xh + (size_t)b * NS * ND;
  ushort_t* xlb = xl + (size_t)b * NS * ND;
  #pragma unroll
  for (int i = 0; i < 4; ++i) {
    const int crel = cg * 4 + i * 64;
    const int col = d0 + crel;
    float4 v0 = *(const float4*)(xb + (size_t)(s0 + r0) * ND + col);
    float4 v1 = *(const float4*)(xb + (size_t)(s0 + r1) * ND + col);
    ushort4 h0, l0, h1, l1;
    h0.x = f2bf(v0.x); l0.x = f2bf(v0.x - bf2f(h0.x));
    h0.y = f2bf(v0.y); l0.y = f2bf(v0.y - bf2f(h0.y));
    h0.z = f2bf(v0.z); l0.z = f2bf(v0.z - bf2f(h0.z));
    h0.w = f2bf(v0.w); l0.w = f2bf(v0.w - bf2f(h0.w));
    h1.x = f2bf(v1.x); l1.x = f2bf(v1.x - bf2f(h1.x));
    h1.y = f2bf(v1.y); l1.y = f2bf(v1.y - bf2f(h1.y));
    h1.z = f2bf(v1.z); l1.z = f2bf(v1.z - bf2f(h1.z));
    h1.w = f2bf(v1.w); l1.w = f2bf(v1.w - bf2f(h1.w));
    *(ushort4*)(xhb + (size_t)(s0 + r0) * ND + col) = h0;
    *(ushort4*)(xlb + (size_t)(s0 + r0) * ND + col) = l0;
    *(ushort4*)(xhb + (size_t)(s0 + r1) * ND + col) = h1;
    *(ushort4*)(xlb + (size_t)(s0 + r1) * ND + col) = l1;
    tile[(crel + 0) * 17 + sp] = (unsigned)h0.x | ((unsigned)h1.x << 16);
    tile[(crel + 1) * 17 + sp] = (unsigned)h0.y | ((unsigned)h1.y << 16);
    tile[(crel + 2) * 17 + sp] = (unsigned)h0.z | ((unsigned)h1.z << 16);
    tile[(crel + 3) * 17 + sp] = (unsigned)h0.w | ((unsigned)h1.w << 16);
  }
  __syncthreads();
  unsigned tmp[16];
  #pragma unroll
  for (int k = 0; k < 16; ++k) tmp[k] = tile[tid * 17 + k];
  ushort_t* dst = xT + ((size_t)b * ND + d0 + tid) * NS + s0;
  #pragma unroll
  for (int k = 0; k < 4; ++k) *(uint4*)(dst + k * 8) = *(uint4*)&tmp[k * 4];
}

// GEMM1 v3: scores = x . L^T, 3-term bf16 split. hi/lo merged in one LDS
// buffer (row = 128 B = 8 granules: kg 0-3 = hi, 4-7 = lo), XOR-swizzled
// (granule kg of row r stored at kg ^ (r&7)) -> fragment reads 2-way (free).
// Epilogue: raw scores + per-row-tile (max, sumexp) partials.
__global__ __launch_bounds__(256, 2)
void gemm1_v3(const ushort_t* __restrict__ xh, const ushort_t* __restrict__ xl,
              const ushort_t* __restrict__ Lh, const ushort_t* __restrict__ Ll,
              float* __restrict__ sc, float* __restrict__ pmax,
              float* __restrict__ psum) {
  __shared__ ushort_t sA[128 * 64];
  __shared__ ushort_t sB[128 * 64];
  const int tid = threadIdx.x;
  const int m0 = blockIdx.y << 7;
  const int n0 = blockIdx.x << 7;
  const int w = tid >> 6, l = tid & 63;
  const int wm = (w >> 1) << 6;
  const int wn = (w & 1) << 6;
  const int lrow = l & 15, quad = l >> 4;

  // staging: lane l of chunk (w*4+q) holds granule g=(w*4+q)*64+l
  // row = g>>3, swizzled pos = l&7, source granule kg = (l&7)^(row&7)
  const int rsub = l >> 3;
  const int kg   = (l & 7) ^ rsub;     // row&7 == l>>3
  const int koff = (kg & 3) << 3;
  const ushort_t* pax = (kg & 4) ? xl : xh;
  const ushort_t* pbx = (kg & 4) ? Ll : Lh;

  // fragment read offset (shorts): hi at (quad^(lrow&7))*8, lo = ^32
  const int sw = (quad ^ (lrow & 7)) << 3;

  floatx4 acc[4][4] = {};

  for (int k0 = 0; k0 < ND; k0 += 32) {
    __syncthreads();
    #pragma unroll
    for (int q = 0; q < 4; ++q) {
      const int row = ((w * 4 + q) << 3) + rsub;
      load_lds16(pax + (size_t)(m0 + row) * ND + k0 + koff, &sA[(w * 4 + q) * 512]);
      load_lds16(pbx + (size_t)(n0 + row) * ND + k0 + koff, &sB[(w * 4 + q) * 512]);
    }
    __syncthreads();
    bf16x8 ah[4], bh[4], t[4];
    #pragma unroll
    for (int i = 0; i < 4; ++i) ah[i] = *(const bf16x8*)&sA[(wm + i*16 + lrow)*64 + sw];
    #pragma unroll
    for (int j = 0; j < 4; ++j) bh[j] = *(const bf16x8*)&sB[(wn + j*16 + lrow)*64 + sw];
    #pragma unroll
    for (int i = 0; i < 4; ++i)
      #pragma unroll
      for (int j = 0; j < 4; ++j)
        acc[i][j] = __builtin_amdgcn_mfma_f32_16x16x32_bf16(ah[i], bh[j], acc[i][j], 0, 0, 0);
    #pragma unroll
    for (int i = 0; i < 4; ++i) t[i] = *(const bf16x8*)&sA[(wm + i*16 + lrow)*64 + (sw ^ 32)];
    #pragma unroll
    for (int i = 0; i < 4; ++i)
      #pragma unroll
      for (int j = 0; j < 4; ++j)
        acc[i][j] = __builtin_amdgcn_mfma_f32_16x16x32_bf16(t[i], bh[j], acc[i][j], 0, 0, 0);
    #pragma unroll
    for (int j = 0; j < 4; ++j) t[j] = *(const bf16x8*)&sB[(wn + j*16 + lrow)*64 + (sw ^ 32)];
    #pragma unroll
    for (int i = 0; i < 4; ++i)
      #pragma unroll
      for (int j = 0; j < 4; ++j)
        acc[i][j] = __builtin_amdgcn_mfma_f32_16x16x32_bf16(ah[i], t[j], acc[i][j], 0, 0, 0);
  }

  // raw scores out. C/D layout: col = lane&15, row = quad*4 + reg
  float* op = sc + (size_t)(m0 + wm + quad * 4) * NC + (n0 + wn + lrow);
  #pragma unroll
  for (int i = 0; i < 4; ++i)
    #pragma unroll
    for (int r = 0; r < 4; ++r)
      #pragma unroll
      for (int j = 0; j < 4; ++j)
        op[(size_t)(i * 16 + r) * NC + j * 16] = acc[i][j][r];

  // per-row partial softmax stats over this block's 128 cols
  __syncthreads();
  float* lmax = (float*)sA;   // [128][2]
  float* lsum = (float*)sB;
  #pragma unroll
  for (int i = 0; i < 4; ++i)
    #pragma unroll
    for (int r = 0; r < 4; ++r) {
      float mx = fmaxf(fmaxf(acc[i][0][r], acc[i][1][r]),
                       fmaxf(acc[i][2][r], acc[i][3][r]));
      #pragma unroll
      for (int off = 1; off < 16; off <<= 1) mx = fmaxf(mx, __shfl_xor(mx, off));
      float se = __expf(acc[i][0][r] - mx) + __expf(acc[i][1][r] - mx) +
                 __expf(acc[i][2][r] - mx) + __expf(acc[i][3][r] - mx);
      #pragma unroll
      for (int off = 1; off < 16; off <<= 1) se += __shfl_xor(se, off);
      if (lrow == 0) {
        const int rl = wm + i * 16 + quad * 4 + r;
        lmax[rl * 2 + (wn >> 6)] = mx;
        lsum[rl * 2 + (wn >> 6)] = se;
      }
    }
  __syncthreads();
  if (tid < 128) {
    const float ma = lmax[tid * 2], mb = lmax[tid * 2 + 1];
    const float M = fmaxf(ma, mb);
    const float Z = lsum[tid * 2] * __expf(ma - M) + lsum[tid * 2 + 1] * __expf(mb - M);
    pmax[(size_t)blockIdx.x * NM + m0 + tid] = M;
    psum[(size_t)blockIdx.x * NM + m0 + tid] = Z;
  }
}

// One-pass softmax + bf16 transpose using gemm1's partials.
// Block = 32 rows. Reads raw scores, writes normalized A fp32 + A_T bf16.
__global__ __launch_bounds__(256)
void softmax_T(float* __restrict__ A, const float* __restrict__ pmax,
               const float* __restrict__ psum, ushort_t* __restrict__ AT) {
  __shared__ float sm[32], sli[32];
  __shared__ unsigned int tile[256 * 17];
  const int s0 = blockIdx.x << 5;
  const int b = s0 >> 11;
  const int sl0 = s0 & (NS - 1);
  const int tid = threadIdx.x;

  if (tid < 32) {
    const int row = s0 + tid;
    float M = -3.0e38f, Z = 0.f;
    for (int n = 0; n < NC / 128; ++n) {
      const float pm = pmax[(size_t)n * NM + row];
      const float ps = psum[(size_t)n * NM + row];
      const float nm = fmaxf(M, pm);
      Z = Z * __expf(M - nm) + ps * __expf(pm - nm);
      M = nm;
    }
    sm[tid] = M; sli[tid] = 1.0f / Z;
  }
  __syncthreads();

  const int sp = tid & 15, cg = tid >> 4;
  const int r0 = 2 * sp, r1 = r0 + 1;
  const float M0 = sm[r0], I0 = sli[r0];
  const float M1 = sm[r1], I1 = sli[r1];
  float* A0 = A + (size_t)(s0 + r0) * NC;
  float* A1 = A + (size_t)(s0 + r1) * NC;
  for (int ch = 0; ch < 16; ++ch) {
    const int cb = ch << 8;
    #pragma unroll
    for (int i = 0; i < 4; ++i) {
      const int crel = cg * 4 + i * 64;
      float4 v0 = *(const float4*)(A0 + cb + crel);
      float4 v1 = *(const float4*)(A1 + cb + crel);
      float4 p0, p1;
      p0.x = __expf(v0.x - M0) * I0; p0.y = __expf(v0.y - M0) * I0;
      p0.z = __expf(v0.z - M0) * I0; p0.w = __expf(v0.w - M0) * I0;
      p1.x = __expf(v1.x - M1) * I1; p1.y = __expf(v1.y - M1) * I1;
      p1.z = __expf(v1.z - M1) * I1; p1.w = __expf(v1.w - M1) * I1;
      *(float4*)(A0 + cb + crel) = p0;
      *(float4*)(A1 + cb + crel) = p1;
      tile[(crel + 0) * 17 + sp] = (unsigned)f2bf(p0.x) | ((unsigned)f2bf(p1.x) << 16);
      tile[(crel + 1) * 17 + sp] = (unsigned)f2bf(p0.y) | ((unsigned)f2bf(p1.y) << 16);
      tile[(crel + 2) * 17 + sp] = (unsigned)f2bf(p0.z) | ((unsigned)f2bf(p1.z) << 16);
      tile[(crel + 3) * 17 + sp] = (unsigned)f2bf(p0.w) | ((unsigned)f2bf(p1.w) << 16);
    }
    __syncthreads();
    unsigned tmp[16];
    #pragma unroll
    for (int k = 0; k < 16; ++k) tmp[k] = tile[tid * 17 + k];
    ushort_t* dst = AT + ((size_t)b * NC + cb + tid) * NS + sl0;
    #pragma unroll
    for (int k = 0; k < 4; ++k) *(uint4*)(dst + k * 8) = *(uint4*)&tmp[k * 4];
    __syncthreads();
  }
}

// GEMM2 v3: O[c,d] = sum_s A_T[c,s] * x_T[d,s]. BK=64 (32 MFMA per
// barrier-pair), XOR-swizzled 128 B LDS rows -> 2-way (free) frag reads.
__global__ __launch_bounds__(256, 2)
void gemm2_v3(const ushort_t* __restrict__ AT, const ushort_t* __restrict__ xT,
              float* __restrict__ out) {
  __shared__ ushort_t sA[128 * 64];
  __shared__ ushort_t sX[128 * 64];
  const int tid = threadIdx.x;
  const int b = blockIdx.z;
  const ushort_t* Ab = AT + (size_t)b * NC * NS;
  const ushort_t* xb = xT + (size_t)b * ND * NS;
  float* ob = out + (size_t)b * NC * ND;
  const int m0 = blockIdx.y << 7;  // c
  const int n0 = blockIdx.x << 7;  // d
  const int w = tid >> 6, l = tid & 63;
  const int wm = (w >> 1) << 6;
  const int wn = (w & 1) << 6;
  const int lrow = l & 15, quad = l >> 4;

  const int rsub = l >> 3;
  const int kg = (l & 7) ^ rsub;

  floatx4 acc[4][4] = {};

  for (int k0 = 0; k0 < NS; k0 += 64) {
    __syncthreads();
    #pragma unroll
    for (int q = 0; q < 4; ++q) {
      const int row = ((w * 4 + q) << 3) + rsub;
      load_lds16(Ab + (size_t)(m0 + row) * NS + k0 + kg * 8, &sA[(w * 4 + q) * 512]);
      load_lds16(xb + (size_t)(n0 + row) * NS + k0 + kg * 8, &sX[(w * 4 + q) * 512]);
    }
    __syncthreads();
    #pragma unroll
    for (int h = 0; h < 2; ++h) {
      const int sw = ((h * 4 + quad) ^ (lrow & 7)) << 3;
      bf16x8 af[4], bg[4];
      #pragma unroll
      for (int i = 0; i < 4; ++i) af[i] = *(const bf16x8*)&sA[(wm + i*16 + lrow)*64 + sw];
      #pragma unroll
      for (int j = 0; j < 4; ++j) bg[j] = *(const bf16x8*)&sX[(wn + j*16 + lrow)*64 + sw];
      #pragma unroll
      for (int i = 0; i < 4; ++i)
        #pragma unroll
        for (int j = 0; j < 4; ++j)
          acc[i][j] = __builtin_amdgcn_mfma_f32_16x16x32_bf16(af[i], bg[j], acc[i][j], 0, 0, 0);
    }
  }

  float* op = ob + (size_t)(m0 + wm + quad * 4) * ND + (n0 + wn + lrow);
  #pragma unroll
  for (int i = 0; i < 4; ++i)
    #pragma unroll
    for (int r = 0; r < 4; ++r)
      #pragma unroll
      for (int j = 0; j < 4; ++j)
        op[(size_t)(i * 16 + r) * ND + j * 16] = acc[i][j][r];
}

// ===========================================================================
// v1 fallback path (no workspace)
// ===========================================================================

__global__ __launch_bounds__(256, 2)
void gemm1_scores(const float* __restrict__ x, const float* __restrict__ L,
                  float* __restrict__ sc) {
  __shared__ unsigned short sAh[128*40];
  __shared__ unsigned short sAl[128*40];
  __shared__ unsigned short sBh[128*40];
  __shared__ unsigned short sBl[128*40];
  const int tid = threadIdx.x;
  const int m0 = blockIdx.y << 7;
  const int n0 = blockIdx.x << 7;
  const int w  = tid >> 6;
  const int l  = tid & 63;
  const int wm = (w >> 1) << 6;
  const int wn = (w & 1) << 6;
  const int lrow = l & 15;
  const int quad = l >> 4;
  floatx4 acc[4][4] = {};
  const int srow = tid >> 3;
  const int scol = (tid & 7) << 2;
  const float* xa = x + (size_t)(m0 + srow) * ND + scol;
  const float* lb = L + (size_t)(n0 + srow) * ND + scol;
  for (int k0 = 0; k0 < ND; k0 += 32) {
    float4 av[4], bv[4];
    #pragma unroll
    for (int p = 0; p < 4; ++p) {
      av[p] = *(const float4*)(xa + (size_t)(p*32) * ND + k0);
      bv[p] = *(const float4*)(lb + (size_t)(p*32) * ND + k0);
    }
    __syncthreads();
    #pragma unroll
    for (int p = 0; p < 4; ++p) {
      const int r = srow + p*32;
      ushort4 h, lo;
      h.x = f2bf(av[p].x); lo.x = f2bf(av[p].x - bf2f(h.x));
      h.y = f2bf(av[p].y); lo.y = f2bf(av[p].y - bf2f(h.y));
      h.z = f2bf(av[p].z); lo.z = f2bf(av[p].z - bf2f(h.z));
      h.w = f2bf(av[p].w); lo.w = f2bf(av[p].w - bf2f(h.w));
      *(ushort4*)&sAh[r*40 + scol] = h;
      *(ushort4*)&sAl[r*40 + scol] = lo;
      h.x = f2bf(bv[p].x); lo.x = f2bf(bv[p].x - bf2f(h.x));
      h.y = f2bf(bv[p].y); lo.y = f2bf(bv[p].y - bf2f(h.y));
      h.z = f2bf(bv[p].z); lo.z = f2bf(bv[p].z - bf2f(h.z));
      h.w = f2bf(bv[p].w); lo.w = f2bf(bv[p].w - bf2f(h.w));
      *(ushort4*)&sBh[r*40 + scol] = h;
      *(ushort4*)&sBl[r*40 + scol] = lo;
    }
    __syncthreads();
    bf16x8 ah[4], bh[4], t[4];
    #pragma unroll
    for (int i = 0; i < 4; ++i) ah[i] = *(const bf16x8*)&sAh[(wm + i*16 + lrow)*40 + quad*8];
    #pragma unroll
    for (int j = 0; j < 4; ++j) bh[j] = *(const bf16x8*)&sBh[(wn + j*16 + lrow)*40 + quad*8];
    #pragma unroll
    for (int i = 0; i < 4; ++i)
      #pragma unroll
      for (int j = 0; j < 4; ++j)
        acc[i][j] = __builtin_amdgcn_mfma_f32_16x16x32_bf16(ah[i], bh[j], acc[i][j], 0, 0, 0);
    #pragma unroll
    for (int i = 0; i < 4; ++i) t[i] = *(const bf16x8*)&sAl[(wm + i*16 + lrow)*40 + quad*8];
    #pragma unroll
    for (int i = 0; i < 4; ++i)
      #pragma unroll
      for (int j = 0; j < 4; ++j)
        acc[i][j] = __builtin_amdgcn_mfma_f32_16x16x32_bf16(t[i], bh[j], acc[i][j], 0, 0, 0);
    #pragma unroll
    for (int j = 0; j < 4; ++j) t[j] = *(const bf16x8*)&sBl[(wn + j*16 + lrow)*40 + quad*8];
    #pragma unroll
    for (int i = 0; i < 4; ++i)
      #pragma unroll
      for (int j = 0; j < 4; ++j)
        acc[i][j] = __builtin_amdgcn_mfma_f32_16x16x32_bf16(ah[i], t[j], acc[i][j], 0, 0, 0);
  }
  float* op = sc + (size_t)(m0 + wm + quad*4) * NC + (n0 + wn + lrow);
  #pragma unroll
  for (int i = 0; i < 4; ++i)
    #pragma unroll
    for (int r = 0; r < 4; ++r)
      #pragma unroll
      for (int j = 0; j < 4; ++j)
        op[(size_t)(i*16 + r) * NC + j*16] = acc[i][j][r];
}

__global__ __launch_bounds__(256)
void softmax_rows(float* __restrict__ A) {
  float* row = A + (size_t)blockIdx.x * NC;
  const int tid = threadIdx.x;
  float4 v[4];
  float mx = -3.0e38f;
  #pragma unroll
  for (int i = 0; i < 4; ++i) {
    v[i] = *(const float4*)(row + (tid << 2) + (i << 10));
    mx = fmaxf(mx, fmaxf(fmaxf(v[i].x, v[i].y), fmaxf(v[i].z, v[i].w)));
  }
  #pragma unroll
  for (int off = 32; off > 0; off >>= 1) mx = fmaxf(mx, __shfl_xor(mx, off));
  __shared__ float red[4];
  if ((tid & 63) == 0) red[tid >> 6] = mx;
  __syncthreads();
  mx = fmaxf(fmaxf(red[0], red[1]), fmaxf(red[2], red[3]));
  float s = 0.f;
  #pragma unroll
  for (int i = 0; i < 4; ++i) {
    v[i].x = __expf(v[i].x - mx); v[i].y = __expf(v[i].y - mx);
    v[i].z = __expf(v[i].z - mx); v[i].w = __expf(v[i].w - mx);
    s += (v[i].x + v[i].y) + (v[i].z + v[i].w);
  }
  #pragma unroll
  for (int off = 32; off > 0; off >>= 1) s += __shfl_xor(s, off);
  __syncthreads();
  if ((tid & 63) == 0) red[tid >> 6] = s;
  __syncthreads();
  s = (red[0] + red[1]) + (red[2] + red[3]);
  const float inv = 1.0f / s;
  #pragma unroll
  for (int i = 0; i < 4; ++i) {
    v[i].x *= inv; v[i].y *= inv; v[i].z *= inv; v[i].w *= inv;
    *(float4*)(row + (tid << 2) + (i << 10)) = v[i];
  }
}

__global__ __launch_bounds__(256, 2)
void gemm2_out(const float* __restrict__ A, const float* __restrict__ x,
               float* __restrict__ out) {
  __shared__ unsigned short sA[128*40];
  __shared__ unsigned short sX[128*40];
  const int tid = threadIdx.x;
  const float* Ab = A + (size_t)blockIdx.z * NS * NC;
  const float* xb = x + (size_t)blockIdx.z * NS * ND;
  float* ob = out + (size_t)blockIdx.z * NC * ND;
  const int m0 = blockIdx.y << 7;
  const int n0 = blockIdx.x << 7;
  const int w  = tid >> 6;
  const int l  = tid & 63;
  const int wm = (w >> 1) << 6;
  const int wn = (w & 1) << 6;
  const int lrow = l & 15;
  const int quad = l >> 4;
  floatx4 acc[4][4] = {};
  const int sp0 = tid & 15;
  const int cg0 = tid >> 4;
  for (int k0 = 0; k0 < NS; k0 += 32) {
    float4 a[2][2], xv[2][2];
    const int s = k0 + sp0*2;
    #pragma unroll
    for (int p = 0; p < 2; ++p) {
      const int c4 = (cg0 + p*16) << 2;
      a[p][0]  = *(const float4*)(Ab + (size_t)s     * NC + m0 + c4);
      a[p][1]  = *(const float4*)(Ab + (size_t)(s+1) * NC + m0 + c4);
      xv[p][0] = *(const float4*)(xb + (size_t)s     * ND + n0 + c4);
      xv[p][1] = *(const float4*)(xb + (size_t)(s+1) * ND + n0 + c4);
    }
    __syncthreads();
    #pragma unroll
    for (int p = 0; p < 2; ++p) {
      const int c4 = (cg0 + p*16) << 2;
      const float* fa0 = (const float*)&a[p][0];
      const float* fa1 = (const float*)&a[p][1];
      const float* fx0 = (const float*)&xv[p][0];
      const float* fx1 = (const float*)&xv[p][1];
      #pragma unroll
      for (int i = 0; i < 4; ++i) {
        const unsigned int pa = (unsigned int)f2bf(fa0[i]) | ((unsigned int)f2bf(fa1[i]) << 16);
        const unsigned int px = (unsigned int)f2bf(fx0[i]) | ((unsigned int)f2bf(fx1[i]) << 16);
        *(unsigned int*)&sA[(c4 + i)*40 + sp0*2] = pa;
        *(unsigned int*)&sX[(c4 + i)*40 + sp0*2] = px;
      }
    }
    __syncthreads();
    bf16x8 af[4], bg[4];
    #pragma unroll
    for (int i = 0; i < 4; ++i) af[i] = *(const bf16x8*)&sA[(wm + i*16 + lrow)*40 + quad*8];
    #pragma unroll
    for (int j = 0; j < 4; ++j) bg[j] = *(const bf16x8*)&sX[(wn + j*16 + lrow)*40 + quad*8];
    #pragma unroll
    for (int i = 0; i < 4; ++i)
      #pragma unroll
      for (int j = 0; j < 4; ++j)
        acc[i][j] = __builtin_amdgcn_mfma_f32_16x16x32_bf16(af[i], bg[j], acc[i][j], 0, 0, 0);
  }
  float* op = ob + (size_t)(m0 + wm + quad*4) * ND + (n0 + wn + lrow);
  #pragma unroll
  for (int i = 0; i < 4; ++i)
    #pragma unroll
    for (int r = 0; r < 4; ++r)
      #pragma unroll
      for (int j = 0; j < 4; ++j)
        op[(size_t)(i*16 + r) * ND + j*16] = acc[i][j][r];
}

// ===========================================================================

extern "C" void kernel_launch(void* const* d_in, const int* in_sizes, int n_in,
                              void* d_out, int out_size, void* d_ws, size_t ws_size,
                              hipStream_t stream) {
  const float* x = (const float*)d_in[0];        // [B,S,D]
  const float* L = (const float*)d_in[1];        // [C,D]
  float* out = (float*)d_out;                    // [B,C,D] then A [B,S,C]
  float* A   = out + (size_t)NB * NC * ND;

  const size_t EL_X  = (size_t)NB * NS * ND;   // 16,777,216
  const size_t EL_L  = (size_t)NC * ND;        //  4,194,304
  const size_t EL_AT = (size_t)NB * NC * NS;   // 67,108,864
  const size_t need  = (3 * EL_X + 2 * EL_L + EL_AT) * sizeof(ushort_t);

  if (ws_size >= need) {
    ushort_t* xh = (ushort_t*)d_ws;
    ushort_t* xl = xh + EL_X;
    ushort_t* xT = xl + EL_X;
    ushort_t* Lh = xT + EL_X;
    ushort_t* Ll = Lh + EL_L;
    ushort_t* AT = Ll + EL_L;
    // softmax partials parked in the (not-yet-written) out0 region of d_out;
    // gemm2_v3 overwrites it afterwards.
    float* pmax = out;                           // [NC/128][NM]
    float* psum = out + (size_t)(NC / 128) * NM; // [NC/128][NM]
    prep_L<<<dim3((NC * ND) / 1024), 256, 0, stream>>>(L, Lh, Ll);
    prep_x<<<dim3(ND / 256, NS / 32, NB), 256, 0, stream>>>(x, xh, xl, xT);
    gemm1_v3<<<dim3(NC / 128, NM / 128), 256, 0, stream>>>(xh, xl, Lh, Ll, A, pmax, psum);
    softmax_T<<<dim3(NM / 32), 256, 0, stream>>>(A, pmax, psum, AT);
    gemm2_v3<<<dim3(ND / 128, NC / 128, NB), 256, 0, stream>>>(AT, xT, out);
  } else {
    gemm1_scores<<<dim3(NC / 128, NM / 128), 256, 0, stream>>>(x, L, A);
    softmax_rows<<<dim3(NM), 256, 0, stream>>>(A);
    gemm2_out<<<dim3(ND / 128, NC / 128, NB), 256, 0, stream>>>(A, x, out);
  }
}